// Round 10
// baseline (134.456 us; speedup 1.0000x reference)
//
#include <hip/hip_runtime.h>

#define EPSF 1e-5f
#define MAGICF 12582912.0f      // 1.5 * 2^23 : adding forces RNE-to-integer in mantissa
#define MLO 0x4B3FFFF8          // bits of MAGICF - 8
#define MHI 0x4B400007          // bits of MAGICF + 7

typedef int    int4v   __attribute__((ext_vector_type(4)));
typedef float  float4v __attribute__((ext_vector_type(4)));

// ---------- ws layout (weights/constants only; intermediates live in LDS) ----------
// w1p : i64 [36*3*64]  conv1 A-fragments (m=co); chunk c (6 cts) = longs [c*1152,(c+1)*1152)
// w3p : i64 [6*18*64]  conv3 B-fragments (n=co), k-order nibble-perm {0,2,4,6,1,3,5,7}
// w2t : i32 [576*4]    dw tap table: per channel {taps0-3, taps4-7, tap8, 0} as bytes
#define W1P_OFF  0
#define W3P_OFF  55296
#define W2T_OFF  110592
#define S1B1_OFF 119808
#define S2B2_OFF 124416
#define S3B3_OFF 129024

// ---- single merged LDS block, hand-placed offsets (all 16B-aligned) ----
// OFF_H1  =     0 : h1 nibbles 120 x 296 = 35520   (live A,B; C: w3p stage)
// OFF_L1  = 35520 : conv1 BN 1152 f32   =  4608   (live A;   C: w3p stage)
// OFF_H2  = 40128 : h2 nibbles 64 x 304 = 19456   (live B,C -- B now overlaps A, so
//                                                  no w1p stage here anymore; A reads
//                                                  w1p from L2, hidden by B's MFMAs)
// OFF_L2  = 59584 : dw BN 1152 f32      =  4608   (live B)
// OFF_L3  = 64192 : conv3 BN 192 f32    =   768   (live C)
// OFF_L2T = 64960 : tap table 576 int4v =  9216   (live B)
// total 74176 -> 2 blocks/CU x 8 waves = 16 waves/CU
#define F1S 296
#define H2S 304

__device__ __forceinline__ float lsq_q(float v, float a) {
    float t = v / a;                       // real division (weight alphas not pow2)
    t = fminf(fmaxf(t, -8.0f), 7.0f);
    return rintf(t);                       // RNE == jnp.round
}

__device__ __forceinline__ long q8pack_w(const float* w, int base, const int* idx, float a) {
    unsigned long long v = 0;
    #pragma unroll
    for (int j = 0; j < 8; ++j) {
        int q = (int)lsq_q(w[base + idx[j]], a);
        v |= (unsigned long long)(q & 255) << (8 * j);
    }
    return (long)v;
}

// ---------------- prep: quantize/pack weights + fused epilogue constants ----------------
// i8 MFMA 16x16x32 fragment layout (HW-verified r2-r5): lane l holds 8 k-bytes
// k = (l>>4)*8 + j at m/n = l&15;  D: col = l&15, row = (l>>4)*4 + reg.
__global__ __launch_bounds__(128)
void prep_w(const float* __restrict__ w1, const float* __restrict__ w2,
            const float* __restrict__ w3,
            const float* aw1, const float* ax1, const float* ax2,
            const float* aw2, const float* ax3, const float* aw3,
            const float* __restrict__ g1, const float* __restrict__ b1,
            const float* __restrict__ m1, const float* __restrict__ v1,
            const float* __restrict__ g2, const float* __restrict__ b2,
            const float* __restrict__ m2, const float* __restrict__ v2,
            const float* __restrict__ g3, const float* __restrict__ b3,
            const float* __restrict__ m3, const float* __restrict__ v3,
            long* __restrict__ w1p, long* __restrict__ w3p,
            int* __restrict__ w2t,
            float* __restrict__ s1b1, float* __restrict__ s2b2,
            float* __restrict__ s3b3) {
    int id = blockIdx.x * 128 + threadIdx.x;
    const int lin[8] = {0, 1, 2, 3, 4, 5, 6, 7};
    const int prm[8] = {0, 2, 4, 6, 1, 3, 5, 7};   // matches nibble lo/hi unpack order
    if (id < 6912) {                        // w1p: ct 0..35, kc 0..2
        int l = id & 63, t = id >> 6;
        int kc = t % 3, ct = t / 3;
        int co = ct * 16 + (l & 15);
        int ci0 = kc * 32 + (l >> 4) * 8;
        w1p[id] = q8pack_w(w1, co * 96 + ci0, lin, aw1[0]);
    } else if (id < 13824) {                // w3p: ct 0..5, kc 0..17 (perm'd k: h2 nibbles)
        int i = id - 6912;
        int l = i & 63, t = i >> 6;
        int kc = t % 18, ct = t / 18;
        int co = ct * 16 + (l & 15);
        int ci0 = kc * 32 + (l >> 4) * 8;
        w3p[i] = q8pack_w(w3, co * 576 + ci0, prm, aw3[0]);
    } else if (id < 14400) {                // w2t: per-channel 9 quantized taps as bytes
        int ch = id - 13824;
        int q[9];
        #pragma unroll
        for (int tp = 0; tp < 9; ++tp)
            q[tp] = (int)lsq_q(w2[ch * 9 + tp], aw2[0]) & 255;
        w2t[ch * 4 + 0] = q[0] | (q[1] << 8) | (q[2] << 16) | (q[3] << 24);
        w2t[ch * 4 + 1] = q[4] | (q[5] << 8) | (q[6] << 16) | (q[7] << 24);
        w2t[ch * 4 + 2] = q[8];
        w2t[ch * 4 + 3] = 0;
    } else if (id < 14976) {                // conv1 fused constants
        int c = id - 14400;
        float s = g1[c] / sqrtf(v1[c] + EPSF);
        float A = aw1[0] * ax1[0];
        float inv = 1.0f / ax2[0];          // exact (alpha = pow2)
        s1b1[c] = A * s * inv;
        s1b1[576 + c] = (b1[c] - m1[c] * s) * inv;
    } else if (id < 15552) {                // dw fused constants
        int c = id - 14976;
        float s = g2[c] / sqrtf(v2[c] + EPSF);
        float A = ax2[0] * aw2[0];
        float inv = 1.0f / ax3[0];
        s2b2[c] = A * s * inv;
        s2b2[576 + c] = (b2[c] - m2[c] * s) * inv;
    } else if (id < 15648) {                // conv3 fused constants
        int c = id - 15552;
        float s = g3[c] / sqrtf(v3[c] + EPSF);
        float A = ax3[0] * aw3[0];
        s3b3[c] = A * s;
        s3b3[96 + c] = b3[c] - m3[c] * s;
    }
}

// ---------------- fused conv1 // dw(MFMA) -> conv3, block = (batch, 2-row strip) ----
// R9 structure with Phase B DISSOLVED into Phase A's pipeline: iteration c computes
// A(chunk c) (waves 0-6, weights from L2) overlapped with B(chunk c-1) (all 8 waves,
// LDS-fed diag MFMAs). B's chains hide A's weight-load latency; the serial B phase
// disappears. C unchanged (w3p staged through dead h1/l1, chunk0 issued in-loop).
__global__ __launch_bounds__(512, 4)
void fused_k(const float* __restrict__ x, const long* __restrict__ w1p,
             const int* __restrict__ w2tg, const long* __restrict__ w3p,
             const float* __restrict__ ax1,
             const float* __restrict__ s1b1g, const float* __restrict__ s2b2g,
             const float* __restrict__ s3b3g, float* __restrict__ out) {
    __shared__ __align__(16) char smem[74176];
    signed char* h1 = (signed char*)smem;                 // A,B
    float*       l1 = (float*)(smem + 35520);             // A
    signed char* h2 = (signed char*)(smem + 40128);       // B,C
    float*       l2 = (float*)(smem + 59584);             // B
    float*       l3 = (float*)(smem + 64192);             // C
    int4v*      l2t = (int4v*)(smem + 64960);             // B
    long*       w3s = (long*)smem;                        // C: 2 x 2304 longs

    const int tid = threadIdx.x;
    const int w = tid >> 6, l = tid & 63;
    const int quad = l >> 4, c16 = l & 15;
    const int qh = quad >> 1, ql = quad & 1;
    const int b = blockIdx.x;          // batch 0..31
    const int r0 = blockIdx.y * 2;     // first output row of strip
    const bool awork = (w < 7);        // waves 0-6 compute A; wave 7 B-only

    // ---- preamble: x prefetch, zero h1, stage tables ----
    const int lp = w * 16 + c16;                 // 0..111: row 0..3, col 0..27
    const int row = lp / 28, col = lp - (lp / 28) * 28;
    const int img_row = r0 - 1 + row;
    const bool valid = awork && ((unsigned)img_row < 28u);
    const int p = min(max(img_row, 0), 27) * 28 + col;
    const float inv1 = 1.0f / ax1[0];            // exact for pow2 alpha

    float xv[3][8];
    if (awork) {
        #pragma unroll
        for (int kc = 0; kc < 3; ++kc) {
            const float* xs = x + (b * 96 + kc * 32 + quad * 8) * 784 + p;
            #pragma unroll
            for (int j = 0; j < 8; ++j) xv[kc][j] = xs[j * 784];
        }
    }
    for (int i = tid; i < 35520 / 16; i += 512)
        ((int4v*)h1)[i] = (int4v){0, 0, 0, 0};
    if (tid < 288) {
        ((int4v*)l1)[tid] = ((const int4v*)s1b1g)[tid];
        ((int4v*)l2)[tid] = ((const int4v*)s2b2g)[tid];
    }
    if (tid < 48) ((int4v*)l3)[tid] = ((const int4v*)s3b3g)[tid];
    for (int i = tid; i < 576; i += 512) l2t[i] = ((const int4v*)w2tg)[i];
    __syncthreads();

    // quantize via magic-add RNE (exact: inv1 pow2 -> product exact; single round)
    long bfr[3];
    if (awork) {
        #pragma unroll
        for (int kc = 0; kc < 3; ++kc) {
            unsigned long long v = 0;
            #pragma unroll
            for (int j = 0; j < 8; ++j) {
                int qi = __float_as_int(fmaf(xv[kc][j], inv1, MAGICF));
                qi = min(max(qi, MLO), MHI);
                v |= (unsigned long long)(qi & 255) << (8 * j);
            }
            bfr[kc] = (long)v;
        }
    }
    const int pos_h = row * 30 + col + 1;        // halo-extended index

    // B-phase per-thread constants (tap-table fragment synthesis)
    const bool vald = ((c16 >> 3) == ql);        // lane's m in this quad's octet?
    const int mh = c16 & 7;
    const int jj = (mh >> 1) | ((mh & 1) << 2);  // byte pos of this m in fragment
    const unsigned shla = 8u * (jj & 3);
    const unsigned mloM = (jj < 4) ? 0xFFFFFFFFu : 0u;
    const unsigned mhiM = ~mloM;
    const unsigned vm  = vald ? 0xFFu : 0u;
    const unsigned vm4 = (vald && qh == 0) ? 0xFFu : 0u;   // tap8 only on quads 0,1
    const unsigned sh0 = qh * 8u;                // taps {0,1} / {4,5}
    const unsigned sh1 = 16u + qh * 8u;          // taps {2,3} / {6,7}

    // C staging state (declared early: chunk0 issued inside the final loop iteration)
    long stg[5];
    auto c3_issue = [&](int ck) {
        #pragma unroll
        for (int k = 0; k < 5; ++k) {
            const int e = tid + k * 512;
            if (e < 2304) {
                const int ct2 = e / 384, rem = e - ct2 * 384;
                stg[k] = w3p[ct2 * 1152 + ck * 384 + rem];
            }
        }
    };
    auto c3_write = [&](int buf) {
        #pragma unroll
        for (int k = 0; k < 5; ++k) {
            const int e = tid + k * 512;
            if (e < 2304) w3s[buf * 2304 + e] = stg[k];
        }
    };

    // ---- merged A//B loop: iteration c = {A(c) waves 0-6} // {B(c-1) all waves} ----
    for (int c = 0; c < 7; ++c) {
        if (c < 6 && awork) {
            // A(c): 6 cts, weights straight from L2 (latency hidden by B below)
            #pragma unroll 2
            for (int ctl = 0; ctl < 6; ++ctl) {
                const int ct = c * 6 + ctl;
                int4v acc; acc[0] = 0; acc[1] = 0; acc[2] = 0; acc[3] = 0;
                #pragma unroll
                for (int kc = 0; kc < 3; ++kc)
                    acc = __builtin_amdgcn_mfma_i32_16x16x32_i8(
                        w1p[(ct * 3 + kc) * 64 + l], bfr[kc], acc, 0, 0, 0);
                const int co0 = ct * 16 + quad * 4;  // 4 consecutive co per lane
                float4v S = *(const float4v*)(l1 + co0);
                float4v B = *(const float4v*)(l1 + 576 + co0);
                int pk = 0;
                #pragma unroll
                for (int r2 = 0; r2 < 4; ++r2) {
                    float t = fmaf((float)acc[r2], S[r2], B[r2]);
                    t = __builtin_amdgcn_fmed3f(t, 0.0f, 7.0f);  // ReLU6+quant clip
                    pk |= (__float_as_int(t + MAGICF) & 15) << (4 * r2);  // RNE nib
                }
                if (valid)
                    *(unsigned short*)(h1 + pos_h * F1S + (co0 >> 1))
                        = (unsigned short)pk;
            }
        }
        if (c >= 1) {
            // B(c-1): 24 tasks (4 pt x 6 ctl) / 8 waves = 3 each; h1 chans of chunk
            // c-1 are complete (previous barrier); h2 writes disjoint from A's h1.
            #pragma unroll
            for (int i = 0; i < 3; ++i) {
                const int t = w + i * 8;             // 0..23
                const int pt = t / 6, ctl = t - (t / 6) * 6;
                const int ct = (c - 1) * 6 + ctl;
                const int pos = pt * 16 + c16;       // 0..63 (56 valid)
                const int posc = min(pos, 55);
                const int row_in = posc / 28, bcol = posc - (posc / 28) * 28;
                const int choff = ct * 8 + ql * 4;   // byte offset of quad's h1 octet
                const int4v tw = l2t[ct * 16 + c16]; // this channel's 9 taps
                int4v acc; acc[0] = 0; acc[1] = 0; acc[2] = 0; acc[3] = 0;
                #pragma unroll
                for (int kc = 0; kc < 5; ++kc) {
                    unsigned bb;
                    if      (kc == 0) bb = ((unsigned)tw[0] >> sh0) & vm;
                    else if (kc == 1) bb = ((unsigned)tw[0] >> sh1) & vm;
                    else if (kc == 2) bb = ((unsigned)tw[1] >> sh0) & vm;
                    else if (kc == 3) bb = ((unsigned)tw[1] >> sh1) & vm;
                    else              bb = ((unsigned)tw[2]) & vm4;
                    const unsigned pl = bb << shla;
                    const long afrag = (long)(((unsigned long long)(pl & mhiM) << 32)
                                              | (pl & mloM));
                    const int tap = min(kc * 2 + qh, 8); // kc=4 qh=1: afrag==0 anyway
                    const int dh = tap / 3 - 1, dc = tap - (tap / 3) * 3 - 1;
                    const int ph = (row_in + 1 + dh) * 30 + (bcol + 1 + dc);
                    const unsigned v = *(const unsigned*)(h1 + ph * F1S + choff);
                    const unsigned lo = v & 0x0F0F0F0Fu;
                    const unsigned hi = (v >> 4) & 0x0F0F0F0Fu;
                    acc = __builtin_amdgcn_mfma_i32_16x16x32_i8(
                        afrag, (long)(((unsigned long long)hi << 32) | lo), acc, 0, 0, 0);
                }
                if (pos < 56) {
                    const int c0 = ct * 16 + quad * 4;
                    float4v S = *(const float4v*)(l2 + c0);
                    float4v B = *(const float4v*)(l2 + 576 + c0);
                    int pk = 0;
                    #pragma unroll
                    for (int r2 = 0; r2 < 4; ++r2) {
                        float tt = fmaf((float)acc[r2], S[r2], B[r2]);
                        tt = __builtin_amdgcn_fmed3f(tt, 0.0f, 7.0f);
                        pk |= (__float_as_int(tt + MAGICF) & 15) << (4 * r2);  // nibble
                    }
                    *(unsigned short*)(h2 + pos * H2S + (c0 >> 1)) = (unsigned short)pk;
                }
            }
        }
        if (c == 6) c3_issue(0);     // C chunk0 loads drain under the final barrier
        __syncthreads();
    }

    // ---- Phase C: conv3 (i8 MFMA, A=h2 nibbles B=w3p-from-LDS) + BN + residual ----
    // 3 kc-chunks staged into the dead h1/l1 region (2 x 2304 longs, double-buffered).
    // 24 tasks / 8 waves = 3 each (t = w + tt*8, guard-free).
    {
        int4v accs[3];
        #pragma unroll
        for (int tt = 0; tt < 3; ++tt) {
            accs[tt][0] = 0; accs[tt][1] = 0; accs[tt][2] = 0; accs[tt][3] = 0;
        }
        auto c3_compute = [&](int ck, int buf) {
            #pragma unroll
            for (int tt = 0; tt < 3; ++tt) {
                const int t = w + tt * 8;            // 0..23, bijective
                const int nt = t / 6, ct = t - (t / 6) * 6;
                const signed char* arow = h2 + (nt * 16 + c16) * H2S + quad * 4;
                #pragma unroll
                for (int kcl = 0; kcl < 6; ++kcl) {
                    const int kc = ck * 6 + kcl;
                    const unsigned va = *(const unsigned*)(arow + kc * 16);
                    const unsigned lo = va & 0x0F0F0F0Fu;
                    const unsigned hi = (va >> 4) & 0x0F0F0F0Fu;
                    accs[tt] = __builtin_amdgcn_mfma_i32_16x16x32_i8(
                        (long)(((unsigned long long)hi << 32) | lo),
                        w3s[buf * 2304 + (ct * 6 + kcl) * 64 + l],
                        accs[tt], 0, 0, 0);
                }
            }
        };

        c3_write(0);                 // chunk0 (issued in-loop; own-reg dep, no barrier)
        c3_issue(1);                 // chunk1 loads drain under barrier below
        __syncthreads();             // buf0 ready (h1/l1 dead since loop end)
        c3_compute(0, 0);
        c3_write(1);                 // chunk1 (loads long since landed)
        c3_issue(2);                 // chunk2 loads drain under barrier below
        __syncthreads();             // buf1 ready; all done reading buf0
        c3_compute(1, 1);
        c3_write(0);                 // chunk2 -> buf0 (safe: buf0 readers done)
        __syncthreads();             // buf0(ck2) ready
        c3_compute(2, 0);

        // epilogue: BN + residual + store
        #pragma unroll
        for (int tt = 0; tt < 3; ++tt) {
            const int t = w + tt * 8;
            const int nt = t / 6, ct = t - (t / 6) * 6;
            const int nloc = nt * 16 + quad * 4;   // 4 consecutive positions
            const int co = ct * 16 + c16;
            const int off = (b * 96 + co) * 784 + r0 * 28 + min(nloc, 52);
            if (nloc < 56) {                       // min(nloc,52)==nloc here
                const float4v xr = *(const float4v*)(x + off);
                const float S = l3[co], Bv = l3[96 + co];
                float4v o;
                #pragma unroll
                for (int r2 = 0; r2 < 4; ++r2)
                    o[r2] = fmaf((float)accs[tt][r2], S, Bv) + xr[r2];
                *(float4v*)(out + off) = o;
            }
        }
    }
}

extern "C" void kernel_launch(void* const* d_in, const int* in_sizes, int n_in,
                              void* d_out, int out_size, void* d_ws, size_t ws_size,
                              hipStream_t stream) {
    const float* x   = (const float*)d_in[0];
    const float* w1  = (const float*)d_in[1];
    const float* w2  = (const float*)d_in[2];
    const float* w3  = (const float*)d_in[3];
    const float* aw1 = (const float*)d_in[4];
    const float* ax1 = (const float*)d_in[5];
    const float* g1  = (const float*)d_in[6];
    const float* b1  = (const float*)d_in[7];
    const float* m1  = (const float*)d_in[8];
    const float* v1  = (const float*)d_in[9];
    const float* aw2 = (const float*)d_in[10];
    const float* ax2 = (const float*)d_in[11];
    const float* g2  = (const float*)d_in[12];
    const float* b2  = (const float*)d_in[13];
    const float* m2  = (const float*)d_in[14];
    const float* v2  = (const float*)d_in[15];
    const float* aw3 = (const float*)d_in[16];
    const float* ax3 = (const float*)d_in[17];
    const float* g3  = (const float*)d_in[18];
    const float* b3  = (const float*)d_in[19];
    const float* m3  = (const float*)d_in[20];
    const float* v3  = (const float*)d_in[21];

    char* ws = (char*)d_ws;
    long* w1p = (long*)(ws + W1P_OFF);
    long* w3p = (long*)(ws + W3P_OFF);
    int*  w2t = (int*)(ws + W2T_OFF);
    float* s1b1 = (float*)(ws + S1B1_OFF);
    float* s2b2 = (float*)(ws + S2B2_OFF);
    float* s3b3 = (float*)(ws + S3B3_OFF);

    float* out = (float*)d_out;

    prep_w<<<123, 128, 0, stream>>>(w1, w2, w3, aw1, ax1, ax2, aw2, ax3, aw3,
                                    g1, b1, m1, v1, g2, b2, m2, v2, g3, b3, m3, v3,
                                    w1p, w3p, w2t, s1b1, s2b2, s3b3);
    dim3 grid(32, 14);
    fused_k<<<grid, 512, 0, stream>>>(x, w1p, w2t, w3p, ax1, s1b1, s2b2, s3b3, out);
}

// Round 11
// 130.798 us; speedup vs baseline: 1.0280x; 1.0280x over previous
//
#include <hip/hip_runtime.h>

#define EPSF 1e-5f
#define MAGICF 12582912.0f      // 1.5 * 2^23 : adding forces RNE-to-integer in mantissa
#define MLO 0x4B3FFFF8          // bits of MAGICF - 8
#define MHI 0x4B400007          // bits of MAGICF + 7

typedef int    int4v   __attribute__((ext_vector_type(4)));
typedef float  float4v __attribute__((ext_vector_type(4)));

// ---------- ws layout (weights/constants only; intermediates live in LDS) ----------
// w1p : i64 [36*3*64]  conv1 A-fragments (m=co); chunk c (6 cts) = longs [c*1152,(c+1)*1152)
// w3p : i64 [6*18*64]  conv3 B-fragments (n=co), k-order nibble-perm {0,2,4,6,1,3,5,7}
// w2t : i32 [576*4]    dw tap table: per channel {taps0-3, taps4-7, tap8, 0} as bytes
#define W1P_OFF  0
#define W3P_OFF  55296
#define W2T_OFF  110592
#define S1B1_OFF 119808
#define S2B2_OFF 124416
#define S3B3_OFF 129024

// ---- single merged LDS block, hand-placed offsets (all 16B-aligned) ----
// OFF_H1  =     0 : h1 nibbles 120 x 296 = 35520   (live A,B; C: w3p stage low part)
// OFF_L1  = 35520 : conv1 BN 1152 f32   =  4608   (live A;   C: w3p stage high part)
// OFF_H2  = 40128 : h2 nibbles 64 x 304 = 19456   (live B,C; A: w1p double-buffer 18432)
// OFF_L2  = 59584 : dw BN 1152 f32      =  4608   (live B)
// OFF_L3  = 64192 : conv3 BN 192 f32    =   768   (live C)
// OFF_L2T = 64960 : tap table 576 int4v =  9216   (live B)
// total 74176 -> 2 blocks/CU x 8 waves = 16 waves/CU
#define F1S 296
#define H2S 304

__device__ __forceinline__ float lsq_q(float v, float a) {
    float t = v / a;                       // real division (weight alphas not pow2)
    t = fminf(fmaxf(t, -8.0f), 7.0f);
    return rintf(t);                       // RNE == jnp.round
}

__device__ __forceinline__ long q8pack_w(const float* w, int base, const int* idx, float a) {
    unsigned long long v = 0;
    #pragma unroll
    for (int j = 0; j < 8; ++j) {
        int q = (int)lsq_q(w[base + idx[j]], a);
        v |= (unsigned long long)(q & 255) << (8 * j);
    }
    return (long)v;
}

// ---------------- prep: quantize/pack weights + fused epilogue constants ----------------
// i8 MFMA 16x16x32 fragment layout (HW-verified r2-r5): lane l holds 8 k-bytes
// k = (l>>4)*8 + j at m/n = l&15;  D: col = l&15, row = (l>>4)*4 + reg.
__global__ __launch_bounds__(128)
void prep_w(const float* __restrict__ w1, const float* __restrict__ w2,
            const float* __restrict__ w3,
            const float* aw1, const float* ax1, const float* ax2,
            const float* aw2, const float* ax3, const float* aw3,
            const float* __restrict__ g1, const float* __restrict__ b1,
            const float* __restrict__ m1, const float* __restrict__ v1,
            const float* __restrict__ g2, const float* __restrict__ b2,
            const float* __restrict__ m2, const float* __restrict__ v2,
            const float* __restrict__ g3, const float* __restrict__ b3,
            const float* __restrict__ m3, const float* __restrict__ v3,
            long* __restrict__ w1p, long* __restrict__ w3p,
            int* __restrict__ w2t,
            float* __restrict__ s1b1, float* __restrict__ s2b2,
            float* __restrict__ s3b3) {
    int id = blockIdx.x * 128 + threadIdx.x;
    const int lin[8] = {0, 1, 2, 3, 4, 5, 6, 7};
    const int prm[8] = {0, 2, 4, 6, 1, 3, 5, 7};   // matches nibble lo/hi unpack order
    if (id < 6912) {                        // w1p: ct 0..35, kc 0..2
        int l = id & 63, t = id >> 6;
        int kc = t % 3, ct = t / 3;
        int co = ct * 16 + (l & 15);
        int ci0 = kc * 32 + (l >> 4) * 8;
        w1p[id] = q8pack_w(w1, co * 96 + ci0, lin, aw1[0]);
    } else if (id < 13824) {                // w3p: ct 0..5, kc 0..17 (perm'd k: h2 nibbles)
        int i = id - 6912;
        int l = i & 63, t = i >> 6;
        int kc = t % 18, ct = t / 18;
        int co = ct * 16 + (l & 15);
        int ci0 = kc * 32 + (l >> 4) * 8;
        w3p[i] = q8pack_w(w3, co * 576 + ci0, prm, aw3[0]);
    } else if (id < 14400) {                // w2t: per-channel 9 quantized taps as bytes
        int ch = id - 13824;
        int q[9];
        #pragma unroll
        for (int tp = 0; tp < 9; ++tp)
            q[tp] = (int)lsq_q(w2[ch * 9 + tp], aw2[0]) & 255;
        w2t[ch * 4 + 0] = q[0] | (q[1] << 8) | (q[2] << 16) | (q[3] << 24);
        w2t[ch * 4 + 1] = q[4] | (q[5] << 8) | (q[6] << 16) | (q[7] << 24);
        w2t[ch * 4 + 2] = q[8];
        w2t[ch * 4 + 3] = 0;
    } else if (id < 14976) {                // conv1 fused constants
        int c = id - 14400;
        float s = g1[c] / sqrtf(v1[c] + EPSF);
        float A = aw1[0] * ax1[0];
        float inv = 1.0f / ax2[0];          // exact (alpha = pow2)
        s1b1[c] = A * s * inv;
        s1b1[576 + c] = (b1[c] - m1[c] * s) * inv;
    } else if (id < 15552) {                // dw fused constants
        int c = id - 14976;
        float s = g2[c] / sqrtf(v2[c] + EPSF);
        float A = ax2[0] * aw2[0];
        float inv = 1.0f / ax3[0];
        s2b2[c] = A * s * inv;
        s2b2[576 + c] = (b2[c] - m2[c] * s) * inv;
    } else if (id < 15648) {                // conv3 fused constants
        int c = id - 15552;
        float s = g3[c] / sqrtf(v3[c] + EPSF);
        float A = ax3[0] * aw3[0];
        s3b3[c] = A * s;
        s3b3[96 + c] = b3[c] - m3[c] * s;
    }
}

// ---------------- fused conv1 -> dw(MFMA) -> conv3, block = (batch, 2-row strip) ----
// R8 structure at 8 waves: wave 7 = dedicated w1p stager in Phase A (producer/consumer
// specialization); Phases B (144/8=18) and C (24/8=3) divide evenly, guard-free.
// [R10 post-mortem: merging B into A's loop regressed -- keep phases serial.]
__global__ __launch_bounds__(512, 4)
void fused_k(const float* __restrict__ x, const long* __restrict__ w1p,
             const int* __restrict__ w2tg, const long* __restrict__ w3p,
             const float* __restrict__ ax1,
             const float* __restrict__ s1b1g, const float* __restrict__ s2b2g,
             const float* __restrict__ s3b3g, float* __restrict__ out) {
    __shared__ __align__(16) char smem[74176];
    signed char* h1 = (signed char*)smem;                 // A,B
    float*       l1 = (float*)(smem + 35520);             // A
    signed char* h2 = (signed char*)(smem + 40128);       // B,C (A: w1p stage)
    float*       l2 = (float*)(smem + 59584);             // B
    float*       l3 = (float*)(smem + 64192);             // C
    int4v*      l2t = (int4v*)(smem + 64960);             // B
    long*    wstage = (long*)h2;                          // A: 2 x 1152 longs
    long*       w3s = (long*)smem;                        // C: 2 x 2304 longs

    const int tid = threadIdx.x;
    const int w = tid >> 6, l = tid & 63;
    const int quad = l >> 4, c16 = l & 15;
    const int qh = quad >> 1, ql = quad & 1;
    const int b = blockIdx.x;          // batch 0..31
    const int r0 = blockIdx.y * 2;     // first output row of strip
    const bool awork = (w < 7);        // waves 0-6 compute Phase A; wave 7 stages w1p

    // ---- Phase A: conv1 (i8 MFMA, A=weights-from-LDS B=acts) -> h1 nibbles ----
    {
        const int lp = w * 16 + c16;                 // 0..111: row 0..3, col 0..27
        const int row = lp / 28, col = lp - (lp / 28) * 28;
        const int img_row = r0 - 1 + row;
        const bool valid = awork && ((unsigned)img_row < 28u);
        const int p = min(max(img_row, 0), 27) * 28 + col;
        const float inv1 = 1.0f / ax1[0];            // exact for pow2 alpha

        // prefetch x into regs FIRST: latency hides behind zero-fill + table staging
        float xv[3][8];
        if (awork) {
            #pragma unroll
            for (int kc = 0; kc < 3; ++kc) {
                const float* xs = x + (b * 96 + kc * 32 + quad * 8) * 784 + p;
                #pragma unroll
                for (int j = 0; j < 8; ++j) xv[kc][j] = xs[j * 784];
            }
        }

        // zero h1 + stage BN/tap tables + w1p chunk 0 while x loads are in flight
        for (int i = tid; i < 35520 / 16; i += 512)
            ((int4v*)h1)[i] = (int4v){0, 0, 0, 0};
        if (tid < 288) {
            ((int4v*)l1)[tid] = ((const int4v*)s1b1g)[tid];
            ((int4v*)l2)[tid] = ((const int4v*)s2b2g)[tid];
        }
        if (tid < 48) ((int4v*)l3)[tid] = ((const int4v*)s3b3g)[tid];
        for (int i = tid; i < 576; i += 512) l2t[i] = ((const int4v*)w2tg)[i];
        for (int i = tid; i < 1152; i += 512) wstage[i] = w1p[i];   // chunk 0 -> buf 0
        __syncthreads();

        // quantize via magic-add RNE (exact: inv1 pow2 -> product exact; single round)
        long bfr[3];
        if (awork) {
            #pragma unroll
            for (int kc = 0; kc < 3; ++kc) {
                unsigned long long v = 0;
                #pragma unroll
                for (int j = 0; j < 8; ++j) {
                    int qi = __float_as_int(fmaf(xv[kc][j], inv1, MAGICF));
                    qi = min(max(qi, MLO), MHI);
                    v |= (unsigned long long)(qi & 255) << (8 * j);
                }
                bfr[kc] = (long)v;
            }
        }
        const int pos_h = row * 30 + col + 1;        // halo-extended index

        // 6 chunks x 6 cts; wave 7 stages chunk c+1 into the free buffer while
        // waves 0-6 compute chunk c (buffers alternate; freed at the prior barrier)
        for (int c = 0; c < 6; ++c) {
            if (!awork) {
                if (c < 5) {
                    const long* src = w1p + (c + 1) * 1152;
                    long stg[18];
                    #pragma unroll
                    for (int k = 0; k < 18; ++k) stg[k] = src[l + k * 64];
                    long* dst = wstage + ((c + 1) & 1) * 1152;
                    #pragma unroll
                    for (int k = 0; k < 18; ++k) dst[l + k * 64] = stg[k];
                }
            } else {
                const long* cur = wstage + (c & 1) * 1152;
                #pragma unroll 3
                for (int ctl = 0; ctl < 6; ++ctl) {
                    const int ct = c * 6 + ctl;
                    int4v acc; acc[0] = 0; acc[1] = 0; acc[2] = 0; acc[3] = 0;
                    #pragma unroll
                    for (int kc = 0; kc < 3; ++kc)
                        acc = __builtin_amdgcn_mfma_i32_16x16x32_i8(
                            cur[(ctl * 3 + kc) * 64 + l], bfr[kc], acc, 0, 0, 0);
                    const int co0 = ct * 16 + quad * 4;  // 4 consecutive co per lane
                    float4v S = *(const float4v*)(l1 + co0);
                    float4v B = *(const float4v*)(l1 + 576 + co0);
                    int pk = 0;
                    #pragma unroll
                    for (int r2 = 0; r2 < 4; ++r2) {
                        float t = fmaf((float)acc[r2], S[r2], B[r2]);
                        t = __builtin_amdgcn_fmed3f(t, 0.0f, 7.0f);  // ReLU6+quant clip
                        pk |= (__float_as_int(t + MAGICF) & 15) << (4 * r2);  // RNE nib
                    }
                    if (valid)
                        *(unsigned short*)(h1 + pos_h * F1S + (co0 >> 1))
                            = (unsigned short)pk;
                }
            }
            __syncthreads();                         // c=5's barrier doubles as A->B
        }
    }

    // ---- Phase B: 3x3 depthwise as block-diagonal i8 MFMA (K=144, 5 chunks) ----
    // A-fragment synthesized from tap table: per (thread, kc) at most ONE nonzero
    // byte (value = w2q[ch][kc*2+qh]) at per-thread-constant byte position j.
    // 144 tasks / 8 waves = 18 each, even.
    {
        const bool vald = ((c16 >> 3) == ql);        // lane's m in this quad's octet?
        const int mh = c16 & 7;
        const int jj = (mh >> 1) | ((mh & 1) << 2);  // byte pos of this m in fragment
        const unsigned shla = 8u * (jj & 3);
        const unsigned mlo = (jj < 4) ? 0xFFFFFFFFu : 0u;
        const unsigned mhi = ~mlo;
        const unsigned vm  = vald ? 0xFFu : 0u;
        const unsigned vm4 = (vald && qh == 0) ? 0xFFu : 0u;   // tap8 only on quads 0,1
        const unsigned sh0 = qh * 8u;                // taps {0,1} / {4,5}
        const unsigned sh1 = 16u + qh * 8u;          // taps {2,3} / {6,7}

        #pragma unroll 2
        for (int t = w; t < 144; t += 8) {
            const int pt = t / 36, ct = t - (t / 36) * 36;
            const int pos = pt * 16 + c16;           // 0..63 (56 valid)
            const int posc = min(pos, 55);
            const int row_in = posc / 28, col = posc - (posc / 28) * 28;
            const int choff = ct * 8 + ql * 4;       // byte offset of quad's h1 octet
            const int4v tw = l2t[ct * 16 + c16];     // this channel's 9 taps
            int4v acc; acc[0] = 0; acc[1] = 0; acc[2] = 0; acc[3] = 0;
            #pragma unroll
            for (int kc = 0; kc < 5; ++kc) {
                unsigned bb;
                if      (kc == 0) bb = ((unsigned)tw[0] >> sh0) & vm;
                else if (kc == 1) bb = ((unsigned)tw[0] >> sh1) & vm;
                else if (kc == 2) bb = ((unsigned)tw[1] >> sh0) & vm;
                else if (kc == 3) bb = ((unsigned)tw[1] >> sh1) & vm;
                else              bb = ((unsigned)tw[2]) & vm4;
                const unsigned pl = bb << shla;
                const long afrag = (long)(((unsigned long long)(pl & mhi) << 32)
                                          | (pl & mlo));
                const int tap = min(kc * 2 + qh, 8); // kc=4 qh=1: afrag==0 anyway
                const int dh = tap / 3 - 1, dc = tap - (tap / 3) * 3 - 1;
                const int pos_h = (row_in + 1 + dh) * 30 + (col + 1 + dc);
                const unsigned v = *(const unsigned*)(h1 + pos_h * F1S + choff);
                const unsigned lo = v & 0x0F0F0F0Fu;
                const unsigned hi = (v >> 4) & 0x0F0F0F0Fu;
                acc = __builtin_amdgcn_mfma_i32_16x16x32_i8(
                    afrag, (long)(((unsigned long long)hi << 32) | lo), acc, 0, 0, 0);
            }
            if (pos < 56) {
                const int c0 = ct * 16 + quad * 4;
                float4v S = *(const float4v*)(l2 + c0);
                float4v B = *(const float4v*)(l2 + 576 + c0);
                int pk = 0;
                #pragma unroll
                for (int r2 = 0; r2 < 4; ++r2) {
                    float tt = fmaf((float)acc[r2], S[r2], B[r2]);
                    tt = __builtin_amdgcn_fmed3f(tt, 0.0f, 7.0f);
                    pk |= (__float_as_int(tt + MAGICF) & 15) << (4 * r2);  // nibble
                }
                *(unsigned short*)(h2 + pos * H2S + (c0 >> 1)) = (unsigned short)pk;
            }
        }
    }

    // ---- Phase C: conv3 (i8 MFMA, A=h2 nibbles B=w3p-from-LDS) + BN + residual ----
    // 3 kc-chunks staged into the dead h1/l1 region (2 x 2304 longs, double-buffered).
    // 24 tasks / 8 waves = 3 each (t = w + tt*8, always valid -- guard-free).
    {
        long stg[5];
        auto c3_issue = [&](int ck) {
            #pragma unroll
            for (int k = 0; k < 5; ++k) {
                const int e = tid + k * 512;
                if (e < 2304) {
                    const int ct2 = e / 384, rem = e - ct2 * 384;
                    stg[k] = w3p[ct2 * 1152 + ck * 384 + rem];
                }
            }
        };
        auto c3_write = [&](int buf) {
            #pragma unroll
            for (int k = 0; k < 5; ++k) {
                const int e = tid + k * 512;
                if (e < 2304) w3s[buf * 2304 + e] = stg[k];
            }
        };

        int4v accs[3];
        #pragma unroll
        for (int tt = 0; tt < 3; ++tt) {
            accs[tt][0] = 0; accs[tt][1] = 0; accs[tt][2] = 0; accs[tt][3] = 0;
        }
        auto c3_compute = [&](int ck, int buf) {
            #pragma unroll
            for (int tt = 0; tt < 3; ++tt) {
                const int t = w + tt * 8;            // 0..23, bijective
                const int nt = t / 6, ct = t - (t / 6) * 6;
                const signed char* arow = h2 + (nt * 16 + c16) * H2S + quad * 4;
                #pragma unroll
                for (int kcl = 0; kcl < 6; ++kcl) {
                    const int kc = ck * 6 + kcl;
                    const unsigned va = *(const unsigned*)(arow + kc * 16);
                    const unsigned lo = va & 0x0F0F0F0Fu;
                    const unsigned hi = (va >> 4) & 0x0F0F0F0Fu;
                    accs[tt] = __builtin_amdgcn_mfma_i32_16x16x32_i8(
                        (long)(((unsigned long long)hi << 32) | lo),
                        w3s[buf * 2304 + (ct * 6 + kcl) * 64 + l],
                        accs[tt], 0, 0, 0);
                }
            }
        };

        c3_issue(0);                 // chunk0 loads drain under the B->C barrier
        __syncthreads();             // B->C: h1/l1 now dead, h2 complete
        c3_write(0);
        c3_issue(1);                 // chunk1 loads drain under barrier below
        __syncthreads();             // buf0 ready
        c3_compute(0, 0);
        c3_write(1);                 // chunk1 (loads long since landed)
        c3_issue(2);                 // chunk2 loads drain under barrier below
        __syncthreads();             // buf1 ready; all done reading buf0
        c3_compute(1, 1);
        c3_write(0);                 // chunk2 -> buf0 (safe: buf0 readers done)
        __syncthreads();             // buf0(ck2) ready
        c3_compute(2, 0);

        // epilogue: BN + residual + store
        #pragma unroll
        for (int tt = 0; tt < 3; ++tt) {
            const int t = w + tt * 8;
            const int nt = t / 6, ct = t - (t / 6) * 6;
            const int nloc = nt * 16 + quad * 4;   // 4 consecutive positions
            const int co = ct * 16 + c16;
            const int off = (b * 96 + co) * 784 + r0 * 28 + min(nloc, 52);
            if (nloc < 56) {                       // min(nloc,52)==nloc here
                const float4v xr = *(const float4v*)(x + off);
                const float S = l3[co], Bv = l3[96 + co];
                float4v o;
                #pragma unroll
                for (int r2 = 0; r2 < 4; ++r2)
                    o[r2] = fmaf((float)accs[tt][r2], S, Bv) + xr[r2];
                *(float4v*)(out + off) = o;
            }
        }
    }
}

extern "C" void kernel_launch(void* const* d_in, const int* in_sizes, int n_in,
                              void* d_out, int out_size, void* d_ws, size_t ws_size,
                              hipStream_t stream) {
    const float* x   = (const float*)d_in[0];
    const float* w1  = (const float*)d_in[1];
    const float* w2  = (const float*)d_in[2];
    const float* w3  = (const float*)d_in[3];
    const float* aw1 = (const float*)d_in[4];
    const float* ax1 = (const float*)d_in[5];
    const float* g1  = (const float*)d_in[6];
    const float* b1  = (const float*)d_in[7];
    const float* m1  = (const float*)d_in[8];
    const float* v1  = (const float*)d_in[9];
    const float* aw2 = (const float*)d_in[10];
    const float* ax2 = (const float*)d_in[11];
    const float* g2  = (const float*)d_in[12];
    const float* b2  = (const float*)d_in[13];
    const float* m2  = (const float*)d_in[14];
    const float* v2  = (const float*)d_in[15];
    const float* aw3 = (const float*)d_in[16];
    const float* ax3 = (const float*)d_in[17];
    const float* g3  = (const float*)d_in[18];
    const float* b3  = (const float*)d_in[19];
    const float* m3  = (const float*)d_in[20];
    const float* v3  = (const float*)d_in[21];

    char* ws = (char*)d_ws;
    long* w1p = (long*)(ws + W1P_OFF);
    long* w3p = (long*)(ws + W3P_OFF);
    int*  w2t = (int*)(ws + W2T_OFF);
    float* s1b1 = (float*)(ws + S1B1_OFF);
    float* s2b2 = (float*)(ws + S2B2_OFF);
    float* s3b3 = (float*)(ws + S3B3_OFF);

    float* out = (float*)d_out;

    prep_w<<<123, 128, 0, stream>>>(w1, w2, w3, aw1, ax1, ax2, aw2, ax3, aw3,
                                    g1, b1, m1, v1, g2, b2, m2, v2, g3, b3, m3, v3,
                                    w1p, w3p, w2t, s1b1, s2b2, s3b3);
    dim3 grid(32, 14);
    fused_k<<<grid, 512, 0, stream>>>(x, w1p, w2t, w3p, ax1, s1b1, s2b2, s3b3, out);
}